// Round 4
// baseline (494.895 us; speedup 1.0000x reference)
//
#include <hip/hip_runtime.h>
#include <stdint.h>

#define L_SZ 110
#define D_SZ 512
#define OUT_W 110
#define A_STRIDE 520   // fallback kernel LDS strides
#define C_STRIDE 136
#define A_ROWS 112
#define ATT_ROWS 112
#define NF_ROWS 112
#define G3_ST 40       // K1 LDS row stride in bf16 elems (32 + 8 pad)

typedef __attribute__((ext_vector_type(8))) __bf16 bf16x8;
typedef __attribute__((ext_vector_type(4))) __bf16 bf16x4;
typedef __attribute__((ext_vector_type(4))) float f32x4;

// Convert W (512x512 fp32, row-major [d][e]) to bf16 in workspace.
__global__ __launch_bounds__(256) void wconv_kernel(const float* __restrict__ W,
                                                    __bf16* __restrict__ wbf) {
    int idx = blockIdx.x * 256 + threadIdx.x;
    float4 w = ((const float4*)W)[idx];
    bf16x4 o;
    o[0] = (__bf16)w.x; o[1] = (__bf16)w.y; o[2] = (__bf16)w.z; o[3] = (__bf16)w.w;
    ((bf16x4*)wbf)[idx] = o;
}

// ---------------- K1: att[b,l,d] = sum_e W[d,e]*nf[b,l,e] ----------------
// m-split LDS-staged GEMM. Grid (8, B): x = mh*4 + cg. Block covers rows
// mh*64..mh*64+63 (T-gated) x cols cg*128..+127. acc 4x2 (32 AGPR), LDS
// 15.4 KB -> 5 blocks/CU for cross-block latency hiding. cg==0 blocks also
// persist converted bf16 A rows to nfbf (folds nfconv).
__global__ __launch_bounds__(256, 5) void att_gemm6_kernel(
    const float* __restrict__ nf, const __bf16* __restrict__ wbf,
    const int* __restrict__ tlenp, __bf16* __restrict__ attws,
    __bf16* __restrict__ nfbf)
{
    __shared__ __bf16 A_lds[64 * G3_ST];    // 5120 B
    __shared__ __bf16 B_lds[128 * G3_ST];   // 10240 B

    const int b   = blockIdx.y;
    const int cg  = blockIdx.x & 3;         // 0..3, 128 cols each
    const int mh  = blockIdx.x >> 2;        // 0..1, 64 rows each
    const int tid = threadIdx.x;
    const int lane = tid & 63;
    const int wave = tid >> 6;
    const int l15  = lane & 15;
    const int quad = lane >> 4;

    int len = tlenp[b];
    if (len > L_SZ) len = L_SZ;
    if (len < 1) len = 1;
    const int T = (len + 15) >> 4;
    if (T <= mh * 4) return;                // whole block uniform exit
    const int Tl = (T - mh * 4 < 4) ? (T - mh * 4) : 4;   // 1..4 m-tiles
    const int rows_needed = T << 4;
    const int rbase = mh << 6;

    const float* nfb = nf + (size_t)b * (L_SZ * D_SZ);

    // staging map: thread covers A row r0 (local) and B rows r0, r0+64, col chunk c8
    const int r0 = tid >> 2;                // 0..63
    const int c8 = (tid & 3) << 3;
    const int ga = rbase + r0;              // global A row
    const int astat = (ga >= rows_needed) ? 0 : ((ga < L_SZ) ? 1 : 2);  // 0=skip,1=load,2=zero

    f32x4 acc[4][2];
    const f32x4 fz = {0.f, 0.f, 0.f, 0.f};
    #pragma unroll
    for (int m = 0; m < 4; ++m) { acc[m][0] = fz; acc[m][1] = fz; }

    float4 abuf[2];
    bf16x8 bbuf[2];

    auto load_tiles = [&](int k0) {
        if (astat == 1) {
            const float* ap = nfb + (size_t)ga * D_SZ + k0 + c8;
            abuf[0] = *(const float4*)ap;
            abuf[1] = *(const float4*)(ap + 4);
        }
        #pragma unroll
        for (int s = 0; s < 2; ++s)
            bbuf[s] = *(const bf16x8*)&wbf[(size_t)(cg * 128 + r0 + 64 * s) * D_SZ + k0 + c8];
    };
    auto store_tiles = [&](int kcur) {
        if (astat) {
            bf16x8 o;
            if (astat == 1) {
                o[0]=(__bf16)abuf[0].x; o[1]=(__bf16)abuf[0].y;
                o[2]=(__bf16)abuf[0].z; o[3]=(__bf16)abuf[0].w;
                o[4]=(__bf16)abuf[1].x; o[5]=(__bf16)abuf[1].y;
                o[6]=(__bf16)abuf[1].z; o[7]=(__bf16)abuf[1].w;
            } else {
                o[0]=o[1]=o[2]=o[3]=o[4]=o[5]=o[6]=o[7]=(__bf16)0.0f;
            }
            *(bf16x8*)&A_lds[r0 * G3_ST + c8] = o;
            if (cg == 0) {   // persist converted tile; rows >= rows_needed never read
                *(bf16x8*)&nfbf[((size_t)b * NF_ROWS + ga) * D_SZ + kcur + c8] = o;
            }
        }
        #pragma unroll
        for (int s = 0; s < 2; ++s)
            *(bf16x8*)&B_lds[(r0 + 64 * s) * G3_ST + c8] = bbuf[s];
    };

    load_tiles(0);
    for (int kt = 0; kt < 16; ++kt) {
        store_tiles(kt << 5);
        __syncthreads();
        if (kt < 15) load_tiles((kt + 1) << 5);   // fly under the MFMAs below
        bf16x8 bfr[2];
        #pragma unroll
        for (int ni = 0; ni < 2; ++ni)
            bfr[ni] = *(const bf16x8*)&B_lds[(wave * 32 + ni * 16 + l15) * G3_ST + quad * 8];
        #pragma unroll
        for (int m = 0; m < 4; ++m) {
            if (m < Tl) {                          // wave-uniform gate
                bf16x8 af = *(const bf16x8*)&A_lds[(m * 16 + l15) * G3_ST + quad * 8];
                acc[m][0] = __builtin_amdgcn_mfma_f32_16x16x32_bf16(af, bfr[0], acc[m][0], 0, 0, 0);
                acc[m][1] = __builtin_amdgcn_mfma_f32_16x16x32_bf16(af, bfr[1], acc[m][1], 0, 0, 0);
            }
        }
        __syncthreads();
    }

    // epilogue: wave-private LDS transpose (C/D layout -> row-major), 16B stores
    __bf16* tw = &A_lds[wave * 16 * G3_ST];
    const size_t obase = (size_t)b * (ATT_ROWS * D_SZ) + cg * 128 + wave * 32;
    const int erow = lane >> 2;
    const int ec8  = (lane & 3) << 3;
    #pragma unroll
    for (int m = 0; m < 4; ++m) {
        if (m < Tl) {
            #pragma unroll
            for (int ni = 0; ni < 2; ++ni)
                #pragma unroll
                for (int r = 0; r < 4; ++r)
                    tw[(quad * 4 + r) * G3_ST + ni * 16 + l15] = (__bf16)acc[m][ni][r];
            bf16x8 v = *(const bf16x8*)&tw[erow * G3_ST + ec8];
            *(bf16x8*)&attws[obase + (size_t)(rbase + m * 16 + erow) * D_SZ + ec8] = v;
        }
    }
}

// ---------------- K2: banded scores + masked softmax (LDS-streamed) ----------------
// Grid (7, B): block = one j-tile tj (exit if tj >= T). Stage A-tile (16 rows
// nfbf) + 3 attws tiles into LDS via block-wide coalesced 16B loads with XOR
// swizzle (chunk ^= row&7, same on write and read -> conflict-minimal reads).
// Waves 0..2 compute tile t=wave (16 MFMAs from LDS); scores to LDS; 256-thread
// masked softmax identical in math to the verified version.
__global__ __launch_bounds__(256) void band4_kernel(
    const __bf16* __restrict__ nfbf, const __bf16* __restrict__ attws,
    const int* __restrict__ tlenp, float* __restrict__ out)
{
    __shared__ __bf16 KV[64 * D_SZ];      // rows 0-15: A, 16-31: B0, 32-47: B1, 48-63: B2 (64 KB)
    __shared__ float S[16 * 52];          // scores [j_local][t*16 + l_local]

    const int tj = blockIdx.x;            // 0..6
    const int b  = blockIdx.y;
    const int tid = threadIdx.x;
    const int lane = tid & 63;
    const int wave = tid >> 6;
    const int l15 = lane & 15;
    const int quad = lane >> 4;

    int len = tlenp[b];
    if (len > L_SZ) len = L_SZ;
    if (len < 1) len = 1;
    const int T = (len + 15) >> 4;
    if (tj >= T) return;                  // whole block uniform exit

    bool tv[3];
    #pragma unroll
    for (int t = 0; t < 3; ++t) {
        int tl = tj - 1 + t;
        tv[t] = (tl >= 0) && (tl < T);
    }

    // ---- stage: wave w covers LDS rows w*16..w*16+15; w==0 -> A, else B[w-1]
    {
        const int bt = wave - 1;
        const bool do_stage = (wave == 0) || tv[bt];
        if (do_stage) {
            const __bf16* gsrc = (wave == 0)
                ? &nfbf[((size_t)b * NF_ROWS + (tj << 4)) * D_SZ]
                : &attws[((size_t)b * ATT_ROWS + ((tj - 1 + bt) << 4)) * D_SZ];
            __bf16* lbase = &KV[(size_t)(wave * 16) * D_SZ];
            bf16x8 st[16];
            #pragma unroll
            for (int i = 0; i < 16; ++i)
                st[i] = *(const bf16x8*)&gsrc[(size_t)i * D_SZ + (lane << 3)];
            #pragma unroll
            for (int i = 0; i < 16; ++i) {
                int ch = lane ^ (i & 7);            // XOR swizzle (write side)
                *(bf16x8*)&lbase[i * D_SZ + (ch << 3)] = st[i];
            }
        }
    }
    __syncthreads();

    // ---- compute: wave w in {0,1,2} computes tile t = w
    if (wave < 3 && tv[wave]) {
        const __bf16* arow = &KV[0];
        const __bf16* brow = &KV[(size_t)((wave + 1) * 16) * D_SZ];
        const f32x4 fz = {0.f, 0.f, 0.f, 0.f};
        f32x4 acc = fz;
        #pragma unroll
        for (int kt = 0; kt < 16; ++kt) {
            int ca = (kt * 4 + quad) ^ (l15 & 7);   // XOR swizzle (read side)
            bf16x8 af = *(const bf16x8*)&arow[l15 * D_SZ + (ca << 3)];
            bf16x8 bf = *(const bf16x8*)&brow[l15 * D_SZ + (ca << 3)];
            acc = __builtin_amdgcn_mfma_f32_16x16x32_bf16(af, bf, acc, 0, 0, 0);
        }
        #pragma unroll
        for (int r = 0; r < 4; ++r)
            S[(quad * 4 + r) * 52 + wave * 16 + l15] = acc[r];
    }
    __syncthreads();

    // ---- masked softmax: thread = (row, col): row = tid>>4, col = tid&15
    const int srow = tid >> 4;            // 0..15 -> j_local
    const int sc   = tid & 15;            // 0..15 -> l_local
    const int j = (tj << 4) + srow;
    float* outb = out + (size_t)b * (L_SZ * OUT_W);

    float v[3]; bool mk[3];
    float vmax = -3.0e38f;
    #pragma unroll
    for (int t = 0; t < 3; ++t) {
        int tl = tj - 1 + t;
        int l = (tl << 4) + sc;
        bool in = tv[t] && (j < len) && (l < len)
                  && (l >= j - 10) && (l <= j + 10);
        float val = in ? S[srow * 52 + t * 16 + sc] : -3.0e38f;
        mk[t] = in; v[t] = val;
        vmax = fmaxf(vmax, val);
    }
    #pragma unroll
    for (int s = 1; s < 16; s <<= 1)
        vmax = fmaxf(vmax, __shfl_xor(vmax, s, 16));
    float e[3]; float esum = 0.f;
    #pragma unroll
    for (int t = 0; t < 3; ++t) {
        e[t] = mk[t] ? __expf(v[t] - vmax) : 0.f;
        esum += e[t];
    }
    #pragma unroll
    for (int s = 1; s < 16; s <<= 1)
        esum += __shfl_xor(esum, s, 16);
    float inv = (esum > 0.f) ? (1.0f / esum) : 0.f;
    if (j < OUT_W) {
        #pragma unroll
        for (int t = 0; t < 3; ++t) {
            if (tv[t]) {
                int l = ((tj - 1 + t) << 4) + sc;
                if (l < OUT_W) outb[(size_t)j * OUT_W + l] = e[t] * inv;
            }
        }
    }
}

// ---------------- K1 (old): LDS-staged GEMM, kept as ws-size fallback ----------------
__global__ __launch_bounds__(256, 3) void att_gemm3_kernel(
    const float* __restrict__ nf, const __bf16* __restrict__ wbf,
    const int* __restrict__ tlenp, __bf16* __restrict__ attws)
{
    __shared__ __bf16 A_lds[112 * G3_ST];
    __shared__ __bf16 B_lds[128 * G3_ST];

    const int b   = blockIdx.y;
    const int cg  = blockIdx.x;
    const int tid = threadIdx.x;
    const int lane = tid & 63;
    const int wave = tid >> 6;
    const int l15  = lane & 15;
    const int quad = lane >> 4;

    int len = tlenp[b];
    if (len > L_SZ) len = L_SZ;
    if (len < 1) len = 1;
    const int T = (len + 15) >> 4;
    const int rows_needed = T << 4;

    const float* nfb = nf + (size_t)b * (L_SZ * D_SZ);

    const int r0 = tid >> 2;
    const int c8 = (tid & 3) << 3;
    const int rows2[2] = { r0, r0 + 64 };
    int stat[2];
    #pragma unroll
    for (int s = 0; s < 2; ++s) {
        int r = rows2[s];
        stat[s] = (r >= rows_needed) ? 0 : ((r < L_SZ) ? 1 : 2);
    }

    f32x4 acc[7][2];
    const f32x4 fz = {0.f, 0.f, 0.f, 0.f};
    #pragma unroll
    for (int m = 0; m < 7; ++m) { acc[m][0] = fz; acc[m][1] = fz; }

    float4 abuf[2][2];
    bf16x8 bbuf[2];

    auto load_tiles = [&](int k0) {
        #pragma unroll
        for (int s = 0; s < 2; ++s) {
            if (stat[s] == 1) {
                const float* ap = nfb + (size_t)rows2[s] * D_SZ + k0 + c8;
                abuf[s][0] = *(const float4*)ap;
                abuf[s][1] = *(const float4*)(ap + 4);
            }
            bbuf[s] = *(const bf16x8*)&wbf[(size_t)(cg * 128 + rows2[s]) * D_SZ + k0 + c8];
        }
    };
    auto store_tiles = [&]() {
        #pragma unroll
        for (int s = 0; s < 2; ++s) {
            if (stat[s]) {
                bf16x8 o;
                if (stat[s] == 1) {
                    o[0]=(__bf16)abuf[s][0].x; o[1]=(__bf16)abuf[s][0].y;
                    o[2]=(__bf16)abuf[s][0].z; o[3]=(__bf16)abuf[s][0].w;
                    o[4]=(__bf16)abuf[s][1].x; o[5]=(__bf16)abuf[s][1].y;
                    o[6]=(__bf16)abuf[s][1].z; o[7]=(__bf16)abuf[s][1].w;
                } else {
                    o[0]=o[1]=o[2]=o[3]=o[4]=o[5]=o[6]=o[7]=(__bf16)0.0f;
                }
                *(bf16x8*)&A_lds[rows2[s] * G3_ST + c8] = o;
            }
            *(bf16x8*)&B_lds[rows2[s] * G3_ST + c8] = bbuf[s];
        }
    };

    load_tiles(0);
    for (int kt = 0; kt < 16; ++kt) {
        store_tiles();
        __syncthreads();
        if (kt < 15) load_tiles((kt + 1) << 5);
        bf16x8 bfr[2];
        #pragma unroll
        for (int ni = 0; ni < 2; ++ni)
            bfr[ni] = *(const bf16x8*)&B_lds[(wave * 32 + ni * 16 + l15) * G3_ST + quad * 8];
        #pragma unroll
        for (int m = 0; m < 7; ++m) {
            if (m < T) {
                bf16x8 af = *(const bf16x8*)&A_lds[(m * 16 + l15) * G3_ST + quad * 8];
                acc[m][0] = __builtin_amdgcn_mfma_f32_16x16x32_bf16(af, bfr[0], acc[m][0], 0, 0, 0);
                acc[m][1] = __builtin_amdgcn_mfma_f32_16x16x32_bf16(af, bfr[1], acc[m][1], 0, 0, 0);
            }
        }
        __syncthreads();
    }

    __bf16* tw = &A_lds[wave * 16 * G3_ST];
    const size_t obase = (size_t)b * (ATT_ROWS * D_SZ) + cg * 128 + wave * 32;
    const int erow = lane >> 2;
    const int ec8  = (lane & 3) << 3;
    #pragma unroll
    for (int m = 0; m < 7; ++m) {
        if (m < T) {
            #pragma unroll
            for (int ni = 0; ni < 2; ++ni)
                #pragma unroll
                for (int r = 0; r < 4; ++r)
                    tw[(quad * 4 + r) * G3_ST + ni * 16 + l15] = (__bf16)acc[m][ni][r];
            bf16x8 v = *(const bf16x8*)&tw[erow * G3_ST + ec8];
            *(bf16x8*)&attws[obase + (size_t)(m * 16 + erow) * D_SZ + ec8] = v;
        }
    }
}

// ---------------- K2 (old): fp32-nf band kernel, kept as ws-size fallback ----------------
__global__ __launch_bounds__(256) void band_kernel(
    const float* __restrict__ nf, const __bf16* __restrict__ attws,
    const int* __restrict__ tlenp, float* __restrict__ out)
{
    const int b = blockIdx.x;
    const int tid = threadIdx.x;
    const int lane = tid & 63;
    const int wave = tid >> 6;
    const int l15 = lane & 15;
    const int quad = lane >> 4;

    int len = tlenp[b];
    if (len > L_SZ) len = L_SZ;
    if (len < 1) len = 1;
    const int T = (len + 15) >> 4;

    const float* nfb = nf + (size_t)b * (L_SZ * D_SZ);
    float* outb = out + (size_t)b * (L_SZ * OUT_W);

    const f32x4 fz = {0.f, 0.f, 0.f, 0.f};
    f32x4 accS[2][3];
    #pragma unroll
    for (int i = 0; i < 2; ++i)
        #pragma unroll
        for (int t = 0; t < 3; ++t) accS[i][t] = fz;

    #pragma unroll
    for (int i = 0; i < 2; ++i) {
        const int tj = wave + (i << 2);
        if (tj < T) {
            int jr = (tj << 4) + l15;
            if (jr > L_SZ - 1) jr = L_SZ - 1;
            const float* ap0 = &nfb[(size_t)jr * D_SZ];
            for (int k0 = 0; k0 < D_SZ; k0 += 32) {
                float4 a0 = *(const float4*)(ap0 + k0 + (quad << 3));
                float4 a1 = *(const float4*)(ap0 + k0 + (quad << 3) + 4);
                bf16x8 af;
                af[0] = (__bf16)a0.x; af[1] = (__bf16)a0.y;
                af[2] = (__bf16)a0.z; af[3] = (__bf16)a0.w;
                af[4] = (__bf16)a1.x; af[5] = (__bf16)a1.y;
                af[6] = (__bf16)a1.z; af[7] = (__bf16)a1.w;
                #pragma unroll
                for (int t = 0; t < 3; ++t) {
                    int tl = tj - 1 + t;
                    if (tl >= 0 && tl < T) {
                        bf16x8 bfr = *(const bf16x8*)&attws[((size_t)b * ATT_ROWS + (tl << 4) + l15) * D_SZ + k0 + (quad << 3)];
                        accS[i][t] = __builtin_amdgcn_mfma_f32_16x16x32_bf16(
                            af, bfr, accS[i][t], 0, 0, 0);
                    }
                }
            }
        }
    }

    #pragma unroll
    for (int i = 0; i < 2; ++i) {
        int tj = wave + 4 * i;
        if (tj >= T) continue;
        #pragma unroll
        for (int r = 0; r < 4; ++r) {
            int j = tj * 16 + quad * 4 + r;
            float v[3]; bool mk[3];
            float vmax = -3.0e38f;
            #pragma unroll
            for (int t = 0; t < 3; ++t) {
                int tl = tj - 1 + t;
                int l = tl * 16 + l15;
                bool in = (tl >= 0) && (tl < T) && (j < len) && (l < len)
                          && (l >= j - 10) && (l <= j + 10);
                float val = in ? accS[i][t][r] : -3.0e38f;
                mk[t] = in; v[t] = val;
                vmax = fmaxf(vmax, val);
            }
            #pragma unroll
            for (int s = 1; s < 16; s <<= 1)
                vmax = fmaxf(vmax, __shfl_xor(vmax, s, 16));
            float e[3]; float esum = 0.f;
            #pragma unroll
            for (int t = 0; t < 3; ++t) {
                e[t] = mk[t] ? __expf(v[t] - vmax) : 0.f;
                esum += e[t];
            }
            #pragma unroll
            for (int s = 1; s < 16; s <<= 1)
                esum += __shfl_xor(esum, s, 16);
            float inv = (esum > 0.f) ? (1.0f / esum) : 0.f;
            if (j < OUT_W) {
                #pragma unroll
                for (int t = 0; t < 3; ++t) {
                    int tl = tj - 1 + t;
                    if (tl >= 0 && tl < T) {
                        int l = tl * 16 + l15;
                        if (l < OUT_W) outb[(size_t)j * OUT_W + l] = e[t] * inv;
                    }
                }
            }
        }
    }
}

// ---------------- fallback: round-1 fused kernel ----------------
__global__ __launch_bounds__(256, 1) void edgeatt_kernel(
    const float* __restrict__ nf, const float* __restrict__ Wf,
    const __bf16* __restrict__ wbf, const int* __restrict__ tlenp,
    float* __restrict__ out, int use_wb)
{
    __shared__ __bf16 A_lds[A_ROWS * A_STRIDE];
    __shared__ __bf16 C_lds[A_ROWS * C_STRIDE];

    const int b = blockIdx.x;
    const int tid = threadIdx.x;
    const int lane = tid & 63;
    const int wave = tid >> 6;
    const int l15 = lane & 15;
    const int quad = lane >> 4;

    int len = tlenp[b];
    if (len > L_SZ) len = L_SZ;
    if (len < 1) len = 1;
    const int T = (len + 15) >> 4;

    const float* nfb = nf + (size_t)b * (L_SZ * D_SZ);
    float* outb = out + (size_t)b * (L_SZ * OUT_W);

    {
        int total4 = len * (D_SZ / 4);
        for (int idx = tid; idx < total4; idx += 256) {
            int row = idx >> 7;
            int c4 = idx & 127;
            float4 v = ((const float4*)nfb)[row * 128 + c4];
            bf16x4 o;
            o[0]=(__bf16)v.x; o[1]=(__bf16)v.y; o[2]=(__bf16)v.z; o[3]=(__bf16)v.w;
            *(bf16x4*)&A_lds[row * A_STRIDE + c4 * 4] = o;
        }
        int zr = 16 * T - len;
        if (zr > 0) {
            int per = A_STRIDE / 4;
            int totalz = zr * per;
            for (int idx = tid; idx < totalz; idx += 256) {
                int row = len + idx / per;
                int c4 = idx % per;
                bf16x4 z; z[0]=z[1]=z[2]=z[3]=(__bf16)0.0f;
                *(bf16x4*)&A_lds[row * A_STRIDE + c4 * 4] = z;
            }
        }
    }
    __syncthreads();

    const int wm = wave >> 1, wn = wave & 1;
    const int h = (T + 1) >> 1;
    const int mt_lo = (wm == 0) ? 0 : h;
    const int nmt = ((wm == 0) ? h : T) - mt_lo;

    const f32x4 fzero = {0.f, 0.f, 0.f, 0.f};
    f32x4 accS[2][3];
    #pragma unroll
    for (int i = 0; i < 2; ++i)
        #pragma unroll
        for (int t = 0; t < 3; ++t) accS[i][t] = fzero;

    for (int c = 0; c < 4; ++c) {
        const int d0 = c * 128;
        f32x4 acc1[4][4];
        #pragma unroll
        for (int mi = 0; mi < 4; ++mi)
            #pragma unroll
            for (int ni = 0; ni < 4; ++ni) acc1[mi][ni] = fzero;

        if (nmt > 0) {
            for (int k0 = 0; k0 < D_SZ; k0 += 32) {
                bf16x8 afrag[4], bfrag[4];
                #pragma unroll
                for (int ni = 0; ni < 4; ++ni) {
                    int d = d0 + (wn * 4 + ni) * 16 + l15;
                    if (use_wb) {
                        bfrag[ni] = *(const bf16x8*)&wbf[(size_t)d * D_SZ + k0 + quad * 8];
                    } else {
                        const float* wp = &Wf[(size_t)d * D_SZ + k0 + quad * 8];
                        float4 w0 = *(const float4*)wp;
                        float4 w1 = *(const float4*)(wp + 4);
                        bf16x8 bb;
                        bb[0]=(__bf16)w0.x; bb[1]=(__bf16)w0.y; bb[2]=(__bf16)w0.z; bb[3]=(__bf16)w0.w;
                        bb[4]=(__bf16)w1.x; bb[5]=(__bf16)w1.y; bb[6]=(__bf16)w1.z; bb[7]=(__bf16)w1.w;
                        bfrag[ni] = bb;
                    }
                }
                #pragma unroll
                for (int mi = 0; mi < 4; ++mi) {
                    if (mi < nmt) {
                        int row = (mt_lo + mi) * 16 + l15;
                        afrag[mi] = *(const bf16x8*)&A_lds[row * A_STRIDE + k0 + quad * 8];
                    }
                }
                #pragma unroll
                for (int mi = 0; mi < 4; ++mi) {
                    if (mi < nmt) {
                        #pragma unroll
                        for (int ni = 0; ni < 4; ++ni)
                            acc1[mi][ni] = __builtin_amdgcn_mfma_f32_16x16x32_bf16(
                                afrag[mi], bfrag[ni], acc1[mi][ni], 0, 0, 0);
                    }
                }
            }
        }
        __syncthreads();

        #pragma unroll
        for (int mi = 0; mi < 4; ++mi) {
            if (mi < nmt) {
                int lbase = (mt_lo + mi) * 16 + quad * 4;
                #pragma unroll
                for (int ni = 0; ni < 4; ++ni) {
                    int dloc = (wn * 4 + ni) * 16 + l15;
                    #pragma unroll
                    for (int r = 0; r < 4; ++r)
                        C_lds[(lbase + r) * C_STRIDE + dloc] = (__bf16)acc1[mi][ni][r];
                }
            }
        }
        __syncthreads();

        for (int kk = 0; kk < 128; kk += 32) {
            #pragma unroll
            for (int i = 0; i < 2; ++i) {
                int tj = wave + 4 * i;
                if (tj < T) {
                    bf16x8 aj = *(const bf16x8*)&A_lds[(tj * 16 + l15) * A_STRIDE + d0 + kk + quad * 8];
                    #pragma unroll
                    for (int t = 0; t < 3; ++t) {
                        int tl = tj - 1 + t;
                        if (tl >= 0 && tl < T) {
                            bf16x8 bj = *(const bf16x8*)&C_lds[(tl * 16 + l15) * C_STRIDE + kk + quad * 8];
                            accS[i][t] = __builtin_amdgcn_mfma_f32_16x16x32_bf16(
                                aj, bj, accS[i][t], 0, 0, 0);
                        }
                    }
                }
            }
        }
        __syncthreads();
    }

    #pragma unroll
    for (int i = 0; i < 2; ++i) {
        int tj = wave + 4 * i;
        if (tj >= T) continue;
        #pragma unroll
        for (int r = 0; r < 4; ++r) {
            int j = tj * 16 + quad * 4 + r;
            float v[3]; bool mk[3];
            float vmax = -3.0e38f;
            #pragma unroll
            for (int t = 0; t < 3; ++t) {
                int tl = tj - 1 + t;
                int l = tl * 16 + l15;
                bool in = (tl >= 0) && (tl < T) && (j < len) && (l < len)
                          && (l >= j - 10) && (l <= j + 10);
                float val = in ? accS[i][t][r] : -3.0e38f;
                mk[t] = in; v[t] = val;
                vmax = fmaxf(vmax, val);
            }
            #pragma unroll
            for (int s = 1; s < 16; s <<= 1)
                vmax = fmaxf(vmax, __shfl_xor(vmax, s, 16));
            float e[3]; float esum = 0.f;
            #pragma unroll
            for (int t = 0; t < 3; ++t) {
                e[t] = mk[t] ? __expf(v[t] - vmax) : 0.f;
                esum += e[t];
            }
            #pragma unroll
            for (int s = 1; s < 16; s <<= 1)
                esum += __shfl_xor(esum, s, 16);
            float inv = (esum > 0.f) ? (1.0f / esum) : 0.f;
            if (j < OUT_W) {
                #pragma unroll
                for (int t = 0; t < 3; ++t) {
                    int tl = tj - 1 + t;
                    if (tl >= 0 && tl < T) {
                        int l = tl * 16 + l15;
                        if (l < OUT_W) outb[(size_t)j * OUT_W + l] = e[t] * inv;
                    }
                }
            }
        }
    }
}

extern "C" void kernel_launch(void* const* d_in, const int* in_sizes, int n_in,
                              void* d_out, int out_size, void* d_ws, size_t ws_size,
                              hipStream_t stream) {
    const float* nf = (const float*)d_in[0];
    const float* W  = (const float*)d_in[1];
    const int* tl   = (const int*)d_in[2];
    float* out      = (float*)d_out;
    __bf16* wbf     = (__bf16*)d_ws;
    const int B = in_sizes[2];

    const size_t wb_bytes  = (size_t)D_SZ * D_SZ * sizeof(__bf16);
    const size_t att_bytes = (size_t)B * ATT_ROWS * D_SZ * sizeof(__bf16);
    const size_t nf_bytes  = (size_t)B * NF_ROWS * D_SZ * sizeof(__bf16);
    const int use_wb = (ws_size >= wb_bytes) ? 1 : 0;
    const int fast   = (use_wb && ws_size >= wb_bytes + att_bytes) ? 1 : 0;
    const int fast2  = (fast && ws_size >= wb_bytes + att_bytes + nf_bytes) ? 1 : 0;

    // zero the whole output once; kernels only write the band region
    hipMemsetAsync(d_out, 0, (size_t)out_size * sizeof(float), stream);

    if (use_wb) {
        hipLaunchKernelGGL(wconv_kernel, dim3(256), dim3(256), 0, stream, W, wbf);
    }
    if (fast2) {
        __bf16* attws = (__bf16*)((char*)d_ws + wb_bytes);
        __bf16* nfbf  = (__bf16*)((char*)d_ws + wb_bytes + att_bytes);
        hipLaunchKernelGGL(att_gemm6_kernel, dim3(8, B), dim3(256), 0, stream, nf, wbf, tl, attws, nfbf);
        hipLaunchKernelGGL(band4_kernel, dim3(7, B), dim3(256), 0, stream, nfbf, attws, tl, out);
    } else if (fast) {
        __bf16* attws = (__bf16*)((char*)d_ws + wb_bytes);
        hipLaunchKernelGGL(att_gemm3_kernel, dim3(4, B), dim3(256), 0, stream, nf, wbf, tl, attws);
        hipLaunchKernelGGL(band_kernel, dim3(B), dim3(256), 0, stream, nf, attws, tl, out);
    } else {
        hipLaunchKernelGGL(edgeatt_kernel, dim3(B), dim3(256), 0, stream,
                           nf, W, wbf, tl, out, use_wb);
    }
}

// Round 5
// 401.587 us; speedup vs baseline: 1.2323x; 1.2323x over previous
//
#include <hip/hip_runtime.h>
#include <stdint.h>

#define L_SZ 110
#define D_SZ 512
#define OUT_W 110
#define A_STRIDE 520   // fallback kernel LDS strides
#define C_STRIDE 136
#define A_ROWS 112
#define ATT_ROWS 112
#define NF_ROWS 112
#define G3_ST 40       // BK=32 LDS row stride (32 + 8 pad)
#define G7_ST 72       // BK=64 LDS row stride (64 + 8 pad)

typedef __attribute__((ext_vector_type(8))) __bf16 bf16x8;
typedef __attribute__((ext_vector_type(4))) __bf16 bf16x4;
typedef __attribute__((ext_vector_type(4))) float f32x4;

// Convert W (512x512 fp32, row-major [d][e]) to bf16 in workspace.
__global__ __launch_bounds__(256) void wconv_kernel(const float* __restrict__ W,
                                                    __bf16* __restrict__ wbf) {
    int idx = blockIdx.x * 256 + threadIdx.x;
    float4 w = ((const float4*)W)[idx];
    bf16x4 o;
    o[0] = (__bf16)w.x; o[1] = (__bf16)w.y; o[2] = (__bf16)w.z; o[3] = (__bf16)w.w;
    ((bf16x4*)wbf)[idx] = o;
}

// ---------------- K1: att[b,l,d] = sum_e W[d,e]*nf[b,l,e] ----------------
// Full 112-row block (m-split reverted), BK=64 -> 8 k-steps, 16 barriers
// (vs 32 at BK=32): ~2x compute per global-latency window. XCD-aware block
// remap clusters each b's 4 cg-blocks on one XCD (nf rows L2-reused).
// cg==0 blocks persist converted bf16 A rows to nfbf (folds nfconv).
__global__ __launch_bounds__(256, 3) void att_gemm7_kernel(
    const float* __restrict__ nf, const __bf16* __restrict__ wbf,
    const int* __restrict__ tlenp, __bf16* __restrict__ attws,
    __bf16* __restrict__ nfbf)
{
    __shared__ __bf16 A_lds[112 * G7_ST];   // 16128 B
    __shared__ __bf16 B_lds[128 * G7_ST];   // 18432 B

    const int gid   = blockIdx.x;
    const int total = gridDim.x;
    const int w = ((total & 7) == 0) ? ((gid & 7) * (total >> 3) + (gid >> 3)) : gid;
    const int b  = w >> 2;
    const int cg = w & 3;                    // 0..3, 128 cols each

    const int tid = threadIdx.x;
    const int lane = tid & 63;
    const int wave = tid >> 6;
    const int l15  = lane & 15;
    const int quad = lane >> 4;

    int len = tlenp[b];
    if (len > L_SZ) len = L_SZ;
    if (len < 1) len = 1;
    const int T = (len + 15) >> 4;
    const int rows_needed = T << 4;          // <= 112

    const float* nfb = nf + (size_t)b * (L_SZ * D_SZ);

    // staging map: thread covers rows rowg+32s (s=0..3), col chunk c8 (8 elems of 64)
    const int rowg = tid >> 3;               // 0..31
    const int c8   = (tid & 7) << 3;         // 0..56
    int astat[4];                            // 0=skip, 1=load, 2=zero
    #pragma unroll
    for (int s = 0; s < 4; ++s) {
        int r = rowg + 32 * s;
        astat[s] = (r >= rows_needed) ? 0 : ((r < L_SZ) ? 1 : 2);
    }

    f32x4 acc[7][2];
    const f32x4 fz = {0.f, 0.f, 0.f, 0.f};
    #pragma unroll
    for (int m = 0; m < 7; ++m) { acc[m][0] = fz; acc[m][1] = fz; }

    float4 abuf[4][2];
    bf16x8 bbuf[4];

    auto load_tiles = [&](int k0) {
        #pragma unroll
        for (int s = 0; s < 4; ++s) {
            int r = rowg + 32 * s;
            if (astat[s] == 1) {
                const float* ap = nfb + (size_t)r * D_SZ + k0 + c8;
                abuf[s][0] = *(const float4*)ap;
                abuf[s][1] = *(const float4*)(ap + 4);
            }
            bbuf[s] = *(const bf16x8*)&wbf[(size_t)(cg * 128 + r) * D_SZ + k0 + c8];
        }
    };
    auto store_tiles = [&](int kcur) {
        #pragma unroll
        for (int s = 0; s < 4; ++s) {
            int r = rowg + 32 * s;
            if (astat[s]) {
                bf16x8 o;
                if (astat[s] == 1) {
                    o[0]=(__bf16)abuf[s][0].x; o[1]=(__bf16)abuf[s][0].y;
                    o[2]=(__bf16)abuf[s][0].z; o[3]=(__bf16)abuf[s][0].w;
                    o[4]=(__bf16)abuf[s][1].x; o[5]=(__bf16)abuf[s][1].y;
                    o[6]=(__bf16)abuf[s][1].z; o[7]=(__bf16)abuf[s][1].w;
                } else {
                    o[0]=o[1]=o[2]=o[3]=o[4]=o[5]=o[6]=o[7]=(__bf16)0.0f;
                }
                *(bf16x8*)&A_lds[r * G7_ST + c8] = o;
                if (cg == 0) {   // persist converted tile; rows >= rows_needed never read
                    *(bf16x8*)&nfbf[((size_t)b * NF_ROWS + r) * D_SZ + kcur + c8] = o;
                }
            }
            *(bf16x8*)&B_lds[r * G7_ST + c8] = bbuf[s];
        }
    };

    load_tiles(0);
    for (int kt = 0; kt < 8; ++kt) {
        store_tiles(kt << 6);
        __syncthreads();
        if (kt < 7) load_tiles((kt + 1) << 6);   // fly under the MFMAs below
        #pragma unroll
        for (int kk = 0; kk < 64; kk += 32) {
            bf16x8 bfr[2];
            #pragma unroll
            for (int ni = 0; ni < 2; ++ni)
                bfr[ni] = *(const bf16x8*)&B_lds[(wave * 32 + ni * 16 + l15) * G7_ST + kk + quad * 8];
            #pragma unroll
            for (int m = 0; m < 7; ++m) {
                if (m < T) {                     // wave-uniform gate
                    bf16x8 af = *(const bf16x8*)&A_lds[(m * 16 + l15) * G7_ST + kk + quad * 8];
                    acc[m][0] = __builtin_amdgcn_mfma_f32_16x16x32_bf16(af, bfr[0], acc[m][0], 0, 0, 0);
                    acc[m][1] = __builtin_amdgcn_mfma_f32_16x16x32_bf16(af, bfr[1], acc[m][1], 0, 0, 0);
                }
            }
        }
        __syncthreads();
    }

    // epilogue: wave-private LDS transpose (C/D layout -> row-major), 16B stores
    __bf16* tw = &A_lds[wave * 16 * G3_ST];
    const size_t obase = (size_t)b * (ATT_ROWS * D_SZ) + cg * 128 + wave * 32;
    const int erow = lane >> 2;
    const int ec8  = (lane & 3) << 3;
    #pragma unroll
    for (int m = 0; m < 7; ++m) {
        if (m < T) {
            #pragma unroll
            for (int ni = 0; ni < 2; ++ni)
                #pragma unroll
                for (int r = 0; r < 4; ++r)
                    tw[(quad * 4 + r) * G3_ST + ni * 16 + l15] = (__bf16)acc[m][ni][r];
            bf16x8 v = *(const bf16x8*)&tw[erow * G3_ST + ec8];
            *(bf16x8*)&attws[obase + (size_t)(m * 16 + erow) * D_SZ + ec8] = v;
        }
    }
}

// ---------------- K2: banded scores + masked softmax (LDS-streamed) ----------------
// band4 structure (verified round-4) + XCD-aware remap: all 7 tj-blocks of a b
// land on one XCD so the up-to-3x attws tile re-reads hit that XCD's L2.
__global__ __launch_bounds__(256) void band5_kernel(
    const __bf16* __restrict__ nfbf, const __bf16* __restrict__ attws,
    const int* __restrict__ tlenp, float* __restrict__ out)
{
    __shared__ __bf16 KV[64 * D_SZ];      // rows 0-15: A, 16-31: B0, 32-47: B1, 48-63: B2 (64 KB)
    __shared__ float S[16 * 52];          // scores [j_local][t*16 + l_local]

    const int gid   = blockIdx.x;
    const int total = gridDim.x;
    const int wkid = ((total & 7) == 0) ? ((gid & 7) * (total >> 3) + (gid >> 3)) : gid;
    const int b  = wkid / 7;
    const int tj = wkid - b * 7;          // 0..6

    const int tid = threadIdx.x;
    const int lane = tid & 63;
    const int wave = tid >> 6;
    const int l15 = lane & 15;
    const int quad = lane >> 4;

    int len = tlenp[b];
    if (len > L_SZ) len = L_SZ;
    if (len < 1) len = 1;
    const int T = (len + 15) >> 4;
    if (tj >= T) return;                  // whole block uniform exit

    bool tv[3];
    #pragma unroll
    for (int t = 0; t < 3; ++t) {
        int tl = tj - 1 + t;
        tv[t] = (tl >= 0) && (tl < T);
    }

    // ---- stage: wave w covers LDS rows w*16..w*16+15; w==0 -> A, else B[w-1]
    {
        const int bt = wave - 1;
        const bool do_stage = (wave == 0) || tv[bt];
        if (do_stage) {
            const __bf16* gsrc = (wave == 0)
                ? &nfbf[((size_t)b * NF_ROWS + (tj << 4)) * D_SZ]
                : &attws[((size_t)b * ATT_ROWS + ((tj - 1 + bt) << 4)) * D_SZ];
            __bf16* lbase = &KV[(size_t)(wave * 16) * D_SZ];
            bf16x8 st[16];
            #pragma unroll
            for (int i = 0; i < 16; ++i)
                st[i] = *(const bf16x8*)&gsrc[(size_t)i * D_SZ + (lane << 3)];
            #pragma unroll
            for (int i = 0; i < 16; ++i) {
                int ch = lane ^ (i & 7);            // XOR swizzle (write side)
                *(bf16x8*)&lbase[i * D_SZ + (ch << 3)] = st[i];
            }
        }
    }
    __syncthreads();

    // ---- compute: wave w in {0,1,2} computes tile t = w
    if (wave < 3 && tv[wave]) {
        const __bf16* arow = &KV[0];
        const __bf16* brow = &KV[(size_t)((wave + 1) * 16) * D_SZ];
        const f32x4 fz = {0.f, 0.f, 0.f, 0.f};
        f32x4 acc = fz;
        #pragma unroll
        for (int kt = 0; kt < 16; ++kt) {
            int ca = (kt * 4 + quad) ^ (l15 & 7);   // XOR swizzle (read side)
            bf16x8 af = *(const bf16x8*)&arow[l15 * D_SZ + (ca << 3)];
            bf16x8 bf = *(const bf16x8*)&brow[l15 * D_SZ + (ca << 3)];
            acc = __builtin_amdgcn_mfma_f32_16x16x32_bf16(af, bf, acc, 0, 0, 0);
        }
        #pragma unroll
        for (int r = 0; r < 4; ++r)
            S[(quad * 4 + r) * 52 + wave * 16 + l15] = acc[r];
    }
    __syncthreads();

    // ---- masked softmax: thread = (row, col): row = tid>>4, col = tid&15
    const int srow = tid >> 4;            // 0..15 -> j_local
    const int sc   = tid & 15;            // 0..15 -> l_local
    const int j = (tj << 4) + srow;
    float* outb = out + (size_t)b * (L_SZ * OUT_W);

    float v[3]; bool mk[3];
    float vmax = -3.0e38f;
    #pragma unroll
    for (int t = 0; t < 3; ++t) {
        int tl = tj - 1 + t;
        int l = (tl << 4) + sc;
        bool in = tv[t] && (j < len) && (l < len)
                  && (l >= j - 10) && (l <= j + 10);
        float val = in ? S[srow * 52 + t * 16 + sc] : -3.0e38f;
        mk[t] = in; v[t] = val;
        vmax = fmaxf(vmax, val);
    }
    #pragma unroll
    for (int s = 1; s < 16; s <<= 1)
        vmax = fmaxf(vmax, __shfl_xor(vmax, s, 16));
    float e[3]; float esum = 0.f;
    #pragma unroll
    for (int t = 0; t < 3; ++t) {
        e[t] = mk[t] ? __expf(v[t] - vmax) : 0.f;
        esum += e[t];
    }
    #pragma unroll
    for (int s = 1; s < 16; s <<= 1)
        esum += __shfl_xor(esum, s, 16);
    float inv = (esum > 0.f) ? (1.0f / esum) : 0.f;
    if (j < OUT_W) {
        #pragma unroll
        for (int t = 0; t < 3; ++t) {
            if (tv[t]) {
                int l = ((tj - 1 + t) << 4) + sc;
                if (l < OUT_W) outb[(size_t)j * OUT_W + l] = e[t] * inv;
            }
        }
    }
}

// ---------------- K1 (old): LDS-staged GEMM, kept as ws-size fallback ----------------
__global__ __launch_bounds__(256, 3) void att_gemm3_kernel(
    const float* __restrict__ nf, const __bf16* __restrict__ wbf,
    const int* __restrict__ tlenp, __bf16* __restrict__ attws)
{
    __shared__ __bf16 A_lds[112 * G3_ST];
    __shared__ __bf16 B_lds[128 * G3_ST];

    const int b   = blockIdx.y;
    const int cg  = blockIdx.x;
    const int tid = threadIdx.x;
    const int lane = tid & 63;
    const int wave = tid >> 6;
    const int l15  = lane & 15;
    const int quad = lane >> 4;

    int len = tlenp[b];
    if (len > L_SZ) len = L_SZ;
    if (len < 1) len = 1;
    const int T = (len + 15) >> 4;
    const int rows_needed = T << 4;

    const float* nfb = nf + (size_t)b * (L_SZ * D_SZ);

    const int r0 = tid >> 2;
    const int c8 = (tid & 3) << 3;
    const int rows2[2] = { r0, r0 + 64 };
    int stat[2];
    #pragma unroll
    for (int s = 0; s < 2; ++s) {
        int r = rows2[s];
        stat[s] = (r >= rows_needed) ? 0 : ((r < L_SZ) ? 1 : 2);
    }

    f32x4 acc[7][2];
    const f32x4 fz = {0.f, 0.f, 0.f, 0.f};
    #pragma unroll
    for (int m = 0; m < 7; ++m) { acc[m][0] = fz; acc[m][1] = fz; }

    float4 abuf[2][2];
    bf16x8 bbuf[2];

    auto load_tiles = [&](int k0) {
        #pragma unroll
        for (int s = 0; s < 2; ++s) {
            if (stat[s] == 1) {
                const float* ap = nfb + (size_t)rows2[s] * D_SZ + k0 + c8;
                abuf[s][0] = *(const float4*)ap;
                abuf[s][1] = *(const float4*)(ap + 4);
            }
            bbuf[s] = *(const bf16x8*)&wbf[(size_t)(cg * 128 + rows2[s]) * D_SZ + k0 + c8];
        }
    };
    auto store_tiles = [&]() {
        #pragma unroll
        for (int s = 0; s < 2; ++s) {
            if (stat[s]) {
                bf16x8 o;
                if (stat[s] == 1) {
                    o[0]=(__bf16)abuf[s][0].x; o[1]=(__bf16)abuf[s][0].y;
                    o[2]=(__bf16)abuf[s][0].z; o[3]=(__bf16)abuf[s][0].w;
                    o[4]=(__bf16)abuf[s][1].x; o[5]=(__bf16)abuf[s][1].y;
                    o[6]=(__bf16)abuf[s][1].z; o[7]=(__bf16)abuf[s][1].w;
                } else {
                    o[0]=o[1]=o[2]=o[3]=o[4]=o[5]=o[6]=o[7]=(__bf16)0.0f;
                }
                *(bf16x8*)&A_lds[rows2[s] * G3_ST + c8] = o;
            }
            *(bf16x8*)&B_lds[rows2[s] * G3_ST + c8] = bbuf[s];
        }
    };

    load_tiles(0);
    for (int kt = 0; kt < 16; ++kt) {
        store_tiles();
        __syncthreads();
        if (kt < 15) load_tiles((kt + 1) << 5);
        bf16x8 bfr[2];
        #pragma unroll
        for (int ni = 0; ni < 2; ++ni)
            bfr[ni] = *(const bf16x8*)&B_lds[(wave * 32 + ni * 16 + l15) * G3_ST + quad * 8];
        #pragma unroll
        for (int m = 0; m < 7; ++m) {
            if (m < T) {
                bf16x8 af = *(const bf16x8*)&A_lds[(m * 16 + l15) * G3_ST + quad * 8];
                acc[m][0] = __builtin_amdgcn_mfma_f32_16x16x32_bf16(af, bfr[0], acc[m][0], 0, 0, 0);
                acc[m][1] = __builtin_amdgcn_mfma_f32_16x16x32_bf16(af, bfr[1], acc[m][1], 0, 0, 0);
            }
        }
        __syncthreads();
    }

    __bf16* tw = &A_lds[wave * 16 * G3_ST];
    const size_t obase = (size_t)b * (ATT_ROWS * D_SZ) + cg * 128 + wave * 32;
    const int erow = lane >> 2;
    const int ec8  = (lane & 3) << 3;
    #pragma unroll
    for (int m = 0; m < 7; ++m) {
        if (m < T) {
            #pragma unroll
            for (int ni = 0; ni < 2; ++ni)
                #pragma unroll
                for (int r = 0; r < 4; ++r)
                    tw[(quad * 4 + r) * G3_ST + ni * 16 + l15] = (__bf16)acc[m][ni][r];
            bf16x8 v = *(const bf16x8*)&tw[erow * G3_ST + ec8];
            *(bf16x8*)&attws[obase + (size_t)(m * 16 + erow) * D_SZ + ec8] = v;
        }
    }
}

// ---------------- K2 (old): fp32-nf band kernel, kept as ws-size fallback ----------------
__global__ __launch_bounds__(256) void band_kernel(
    const float* __restrict__ nf, const __bf16* __restrict__ attws,
    const int* __restrict__ tlenp, float* __restrict__ out)
{
    const int b = blockIdx.x;
    const int tid = threadIdx.x;
    const int lane = tid & 63;
    const int wave = tid >> 6;
    const int l15 = lane & 15;
    const int quad = lane >> 4;

    int len = tlenp[b];
    if (len > L_SZ) len = L_SZ;
    if (len < 1) len = 1;
    const int T = (len + 15) >> 4;

    const float* nfb = nf + (size_t)b * (L_SZ * D_SZ);
    float* outb = out + (size_t)b * (L_SZ * OUT_W);

    const f32x4 fz = {0.f, 0.f, 0.f, 0.f};
    f32x4 accS[2][3];
    #pragma unroll
    for (int i = 0; i < 2; ++i)
        #pragma unroll
        for (int t = 0; t < 3; ++t) accS[i][t] = fz;

    #pragma unroll
    for (int i = 0; i < 2; ++i) {
        const int tj = wave + (i << 2);
        if (tj < T) {
            int jr = (tj << 4) + l15;
            if (jr > L_SZ - 1) jr = L_SZ - 1;
            const float* ap0 = &nfb[(size_t)jr * D_SZ];
            for (int k0 = 0; k0 < D_SZ; k0 += 32) {
                float4 a0 = *(const float4*)(ap0 + k0 + (quad << 3));
                float4 a1 = *(const float4*)(ap0 + k0 + (quad << 3) + 4);
                bf16x8 af;
                af[0] = (__bf16)a0.x; af[1] = (__bf16)a0.y;
                af[2] = (__bf16)a0.z; af[3] = (__bf16)a0.w;
                af[4] = (__bf16)a1.x; af[5] = (__bf16)a1.y;
                af[6] = (__bf16)a1.z; af[7] = (__bf16)a1.w;
                #pragma unroll
                for (int t = 0; t < 3; ++t) {
                    int tl = tj - 1 + t;
                    if (tl >= 0 && tl < T) {
                        bf16x8 bfr = *(const bf16x8*)&attws[((size_t)b * ATT_ROWS + (tl << 4) + l15) * D_SZ + k0 + (quad << 3)];
                        accS[i][t] = __builtin_amdgcn_mfma_f32_16x16x32_bf16(
                            af, bfr, accS[i][t], 0, 0, 0);
                    }
                }
            }
        }
    }

    #pragma unroll
    for (int i = 0; i < 2; ++i) {
        int tj = wave + 4 * i;
        if (tj >= T) continue;
        #pragma unroll
        for (int r = 0; r < 4; ++r) {
            int j = tj * 16 + quad * 4 + r;
            float v[3]; bool mk[3];
            float vmax = -3.0e38f;
            #pragma unroll
            for (int t = 0; t < 3; ++t) {
                int tl = tj - 1 + t;
                int l = tl * 16 + l15;
                bool in = (tl >= 0) && (tl < T) && (j < len) && (l < len)
                          && (l >= j - 10) && (l <= j + 10);
                float val = in ? accS[i][t][r] : -3.0e38f;
                mk[t] = in; v[t] = val;
                vmax = fmaxf(vmax, val);
            }
            #pragma unroll
            for (int s = 1; s < 16; s <<= 1)
                vmax = fmaxf(vmax, __shfl_xor(vmax, s, 16));
            float e[3]; float esum = 0.f;
            #pragma unroll
            for (int t = 0; t < 3; ++t) {
                e[t] = mk[t] ? __expf(v[t] - vmax) : 0.f;
                esum += e[t];
            }
            #pragma unroll
            for (int s = 1; s < 16; s <<= 1)
                esum += __shfl_xor(esum, s, 16);
            float inv = (esum > 0.f) ? (1.0f / esum) : 0.f;
            if (j < OUT_W) {
                #pragma unroll
                for (int t = 0; t < 3; ++t) {
                    int tl = tj - 1 + t;
                    if (tl >= 0 && tl < T) {
                        int l = tl * 16 + l15;
                        if (l < OUT_W) outb[(size_t)j * OUT_W + l] = e[t] * inv;
                    }
                }
            }
        }
    }
}

// ---------------- fallback: round-1 fused kernel ----------------
__global__ __launch_bounds__(256, 1) void edgeatt_kernel(
    const float* __restrict__ nf, const float* __restrict__ Wf,
    const __bf16* __restrict__ wbf, const int* __restrict__ tlenp,
    float* __restrict__ out, int use_wb)
{
    __shared__ __bf16 A_lds[A_ROWS * A_STRIDE];
    __shared__ __bf16 C_lds[A_ROWS * C_STRIDE];

    const int b = blockIdx.x;
    const int tid = threadIdx.x;
    const int lane = tid & 63;
    const int wave = tid >> 6;
    const int l15 = lane & 15;
    const int quad = lane >> 4;

    int len = tlenp[b];
    if (len > L_SZ) len = L_SZ;
    if (len < 1) len = 1;
    const int T = (len + 15) >> 4;

    const float* nfb = nf + (size_t)b * (L_SZ * D_SZ);
    float* outb = out + (size_t)b * (L_SZ * OUT_W);

    {
        int total4 = len * (D_SZ / 4);
        for (int idx = tid; idx < total4; idx += 256) {
            int row = idx >> 7;
            int c4 = idx & 127;
            float4 v = ((const float4*)nfb)[row * 128 + c4];
            bf16x4 o;
            o[0]=(__bf16)v.x; o[1]=(__bf16)v.y; o[2]=(__bf16)v.z; o[3]=(__bf16)v.w;
            *(bf16x4*)&A_lds[row * A_STRIDE + c4 * 4] = o;
        }
        int zr = 16 * T - len;
        if (zr > 0) {
            int per = A_STRIDE / 4;
            int totalz = zr * per;
            for (int idx = tid; idx < totalz; idx += 256) {
                int row = len + idx / per;
                int c4 = idx % per;
                bf16x4 z; z[0]=z[1]=z[2]=z[3]=(__bf16)0.0f;
                *(bf16x4*)&A_lds[row * A_STRIDE + c4 * 4] = z;
            }
        }
    }
    __syncthreads();

    const int wm = wave >> 1, wn = wave & 1;
    const int h = (T + 1) >> 1;
    const int mt_lo = (wm == 0) ? 0 : h;
    const int nmt = ((wm == 0) ? h : T) - mt_lo;

    const f32x4 fzero = {0.f, 0.f, 0.f, 0.f};
    f32x4 accS[2][3];
    #pragma unroll
    for (int i = 0; i < 2; ++i)
        #pragma unroll
        for (int t = 0; t < 3; ++t) accS[i][t] = fzero;

    for (int c = 0; c < 4; ++c) {
        const int d0 = c * 128;
        f32x4 acc1[4][4];
        #pragma unroll
        for (int mi = 0; mi < 4; ++mi)
            #pragma unroll
            for (int ni = 0; ni < 4; ++ni) acc1[mi][ni] = fzero;

        if (nmt > 0) {
            for (int k0 = 0; k0 < D_SZ; k0 += 32) {
                bf16x8 afrag[4], bfrag[4];
                #pragma unroll
                for (int ni = 0; ni < 4; ++ni) {
                    int d = d0 + (wn * 4 + ni) * 16 + l15;
                    if (use_wb) {
                        bfrag[ni] = *(const bf16x8*)&wbf[(size_t)d * D_SZ + k0 + quad * 8];
                    } else {
                        const float* wp = &Wf[(size_t)d * D_SZ + k0 + quad * 8];
                        float4 w0 = *(const float4*)wp;
                        float4 w1 = *(const float4*)(wp + 4);
                        bf16x8 bb;
                        bb[0]=(__bf16)w0.x; bb[1]=(__bf16)w0.y; bb[2]=(__bf16)w0.z; bb[3]=(__bf16)w0.w;
                        bb[4]=(__bf16)w1.x; bb[5]=(__bf16)w1.y; bb[6]=(__bf16)w1.z; bb[7]=(__bf16)w1.w;
                        bfrag[ni] = bb;
                    }
                }
                #pragma unroll
                for (int mi = 0; mi < 4; ++mi) {
                    if (mi < nmt) {
                        int row = (mt_lo + mi) * 16 + l15;
                        afrag[mi] = *(const bf16x8*)&A_lds[row * A_STRIDE + k0 + quad * 8];
                    }
                }
                #pragma unroll
                for (int mi = 0; mi < 4; ++mi) {
                    if (mi < nmt) {
                        #pragma unroll
                        for (int ni = 0; ni < 4; ++ni)
                            acc1[mi][ni] = __builtin_amdgcn_mfma_f32_16x16x32_bf16(
                                afrag[mi], bfrag[ni], acc1[mi][ni], 0, 0, 0);
                    }
                }
            }
        }
        __syncthreads();

        #pragma unroll
        for (int mi = 0; mi < 4; ++mi) {
            if (mi < nmt) {
                int lbase = (mt_lo + mi) * 16 + quad * 4;
                #pragma unroll
                for (int ni = 0; ni < 4; ++ni) {
                    int dloc = (wn * 4 + ni) * 16 + l15;
                    #pragma unroll
                    for (int r = 0; r < 4; ++r)
                        C_lds[(lbase + r) * C_STRIDE + dloc] = (__bf16)acc1[mi][ni][r];
                }
            }
        }
        __syncthreads();

        for (int kk = 0; kk < 128; kk += 32) {
            #pragma unroll
            for (int i = 0; i < 2; ++i) {
                int tj = wave + 4 * i;
                if (tj < T) {
                    bf16x8 aj = *(const bf16x8*)&A_lds[(tj * 16 + l15) * A_STRIDE + d0 + kk + quad * 8];
                    #pragma unroll
                    for (int t = 0; t < 3; ++t) {
                        int tl = tj - 1 + t;
                        if (tl >= 0 && tl < T) {
                            bf16x8 bj = *(const bf16x8*)&C_lds[(tl * 16 + l15) * C_STRIDE + kk + quad * 8];
                            accS[i][t] = __builtin_amdgcn_mfma_f32_16x16x32_bf16(
                                aj, bj, accS[i][t], 0, 0, 0);
                        }
                    }
                }
            }
        }
        __syncthreads();
    }

    #pragma unroll
    for (int i = 0; i < 2; ++i) {
        int tj = wave + 4 * i;
        if (tj >= T) continue;
        #pragma unroll
        for (int r = 0; r < 4; ++r) {
            int j = tj * 16 + quad * 4 + r;
            float v[3]; bool mk[3];
            float vmax = -3.0e38f;
            #pragma unroll
            for (int t = 0; t < 3; ++t) {
                int tl = tj - 1 + t;
                int l = tl * 16 + l15;
                bool in = (tl >= 0) && (tl < T) && (j < len) && (l < len)
                          && (l >= j - 10) && (l <= j + 10);
                float val = in ? accS[i][t][r] : -3.0e38f;
                mk[t] = in; v[t] = val;
                vmax = fmaxf(vmax, val);
            }
            #pragma unroll
            for (int s = 1; s < 16; s <<= 1)
                vmax = fmaxf(vmax, __shfl_xor(vmax, s, 16));
            float e[3]; float esum = 0.f;
            #pragma unroll
            for (int t = 0; t < 3; ++t) {
                e[t] = mk[t] ? __expf(v[t] - vmax) : 0.f;
                esum += e[t];
            }
            #pragma unroll
            for (int s = 1; s < 16; s <<= 1)
                esum += __shfl_xor(esum, s, 16);
            float inv = (esum > 0.f) ? (1.0f / esum) : 0.f;
            if (j < OUT_W) {
                #pragma unroll
                for (int t = 0; t < 3; ++t) {
                    int tl = tj - 1 + t;
                    if (tl >= 0 && tl < T) {
                        int l = tl * 16 + l15;
                        if (l < OUT_W) outb[(size_t)j * OUT_W + l] = e[t] * inv;
                    }
                }
            }
        }
    }
}

extern "C" void kernel_launch(void* const* d_in, const int* in_sizes, int n_in,
                              void* d_out, int out_size, void* d_ws, size_t ws_size,
                              hipStream_t stream) {
    const float* nf = (const float*)d_in[0];
    const float* W  = (const float*)d_in[1];
    const int* tl   = (const int*)d_in[2];
    float* out      = (float*)d_out;
    __bf16* wbf     = (__bf16*)d_ws;
    const int B = in_sizes[2];

    const size_t wb_bytes  = (size_t)D_SZ * D_SZ * sizeof(__bf16);
    const size_t att_bytes = (size_t)B * ATT_ROWS * D_SZ * sizeof(__bf16);
    const size_t nf_bytes  = (size_t)B * NF_ROWS * D_SZ * sizeof(__bf16);
    const int use_wb = (ws_size >= wb_bytes) ? 1 : 0;
    const int fast   = (use_wb && ws_size >= wb_bytes + att_bytes) ? 1 : 0;
    const int fast2  = (fast && ws_size >= wb_bytes + att_bytes + nf_bytes) ? 1 : 0;

    // zero the whole output once; kernels only write the band region
    hipMemsetAsync(d_out, 0, (size_t)out_size * sizeof(float), stream);

    if (use_wb) {
        hipLaunchKernelGGL(wconv_kernel, dim3(256), dim3(256), 0, stream, W, wbf);
    }
    if (fast2) {
        __bf16* attws = (__bf16*)((char*)d_ws + wb_bytes);
        __bf16* nfbf  = (__bf16*)((char*)d_ws + wb_bytes + att_bytes);
        hipLaunchKernelGGL(att_gemm7_kernel, dim3(4 * B), dim3(256), 0, stream, nf, wbf, tl, attws, nfbf);
        hipLaunchKernelGGL(band5_kernel, dim3(7 * B), dim3(256), 0, stream, nfbf, attws, tl, out);
    } else if (fast) {
        __bf16* attws = (__bf16*)((char*)d_ws + wb_bytes);
        hipLaunchKernelGGL(att_gemm3_kernel, dim3(4, B), dim3(256), 0, stream, nf, wbf, tl, attws);
        hipLaunchKernelGGL(band_kernel, dim3(B), dim3(256), 0, stream, nf, attws, tl, out);
    } else {
        hipLaunchKernelGGL(edgeatt_kernel, dim3(B), dim3(256), 0, stream,
                           nf, W, wbf, tl, out, use_wb);
    }
}